// Round 8
// baseline (16.050 us; speedup 1.0000x reference)
//
#include <hip/hip_runtime.h>
#include <math.h>

#define EPS 1e-7f
#define NB_BCE 512    // blocks doing the BCE base-sum role

// BCE-with-logits base term (target-independent part): max(l,0) + log1p(exp(-|l|))
__device__ __forceinline__ float bce_base(float l) {
    return fmaxf(l, 0.0f) + __logf(1.0f + __expf(-fabsf(l)));
}

__device__ __forceinline__ float sigmoidf_(float x) { return 1.0f / (1.0f + expf(-x)); }

// Kernel 1. Grid = 3B/4 + NB_BCE = 896 blocks, 3584 waves, all useful.
//  blocks [0, 3B/4)        : positives work, FOUR (image,level) pairs per block,
//                            one pair per wave, private s_map region per wave,
//                            zero __syncthreads. Channel gathers issued
//                            speculatively before the LDS scatter resolves.
//                            -> ws_pl[pbid] = {box/max(np,1), corr, np, np>0}
//  blocks [3B/4, ..+NB_BCE): grid-stride BCE base sum over channel 0 -> ws_c[...]
// No global atomics, no device fences; plain stores to distinct slots only
// (inter-dispatch flush provides visibility to kernel 2 — proven r2/r5/r6/r7).
__global__ __launch_bounds__(256) void det_main(
    const float* __restrict__ pred0,   // (B,5,52,52)
    const float* __restrict__ pred1,   // (B,5,26,26)
    const float* __restrict__ pred2,   // (B,5,13,13)
    const float* __restrict__ gt,      // (B,32,4)
    float*       ws_c,                 // [NB_BCE]
    float4*      ws_pl,                // [3B]
    int B)
{
    __shared__ int   s_map[4][52 * 52];   // one region per wave (43 KB)
    __shared__ float s_redf[4];

    const int tid = threadIdx.x;
    const int bid = blockIdx.x;
    const int nPL   = 3 * B;
    const int nPosB = nPL >> 2;           // 4 pairs per block

    if (bid >= nPosB) {
        // ---------------- BCE base role ----------------
        const int cbid = bid - nPosB;                      // 0 .. NB_BCE-1
        const unsigned E0 = (unsigned)B * 2704u;
        const unsigned E1 = (unsigned)B * 676u;
        const unsigned E2 = (unsigned)B * 169u;
        const unsigned NV4 = (E0 + E1) >> 2;               // float4 items (both %4==0)
        float acc = 0.0f;

        for (unsigned v = (unsigned)cbid * 256u + tid; v < NV4; v += NB_BCE * 256u) {
            const unsigned idx = v << 2;
            const float* p;
            if (idx < E0) {
                const unsigned b = idx / 2704u;
                const unsigned i = idx - b * 2704u;
                p = pred0 + (size_t)b * 13520u + i;
            } else {
                const unsigned j = idx - E0;
                const unsigned b = j / 676u;
                const unsigned i = j - b * 676u;
                p = pred1 + (size_t)b * 3380u + i;
            }
            const float4 l = *reinterpret_cast<const float4*>(p);
            acc += bce_base(l.x) + bce_base(l.y) + bce_base(l.z) + bce_base(l.w);
        }
        for (unsigned j = (unsigned)cbid * 256u + tid; j < E2; j += NB_BCE * 256u) {
            const unsigned b = j / 169u;
            const unsigned i = j - b * 169u;
            acc += bce_base(pred2[(size_t)b * 845u + i]);
        }

        for (int off = 32; off > 0; off >>= 1) acc += __shfl_down(acc, off);
        if ((tid & 63) == 0) s_redf[tid >> 6] = acc;
        __syncthreads();
        if (tid == 0) ws_c[cbid] = s_redf[0] + s_redf[1] + s_redf[2] + s_redf[3];
        return;
    }

    // ---------------- positives role: one pair per wave, no barriers ----------------
    const int wid  = tid >> 6;             // wave 0..3
    const int lane = tid & 63;
    const int pbid = bid * 4 + wid;        // 0 .. 3B-1
    const int level = pbid % 3;
    const int b     = pbid / 3;

    const float* pred;
    int Wd;
    if (level == 0)      { pred = pred0; Wd = 52; }
    else if (level == 1) { pred = pred1; Wd = 26; }
    else                 { pred = pred2; Wd = 13; }
    const int   HW = Wd * Wd;
    const float S  = (float)Wd;
    const float sc = 1.0f / S;

    int* smap = s_map[wid];

    float box_v = 0.0f, corr_v = 0.0f, np_v = 0.0f;

    if (lane < 32) {
        const int n = lane;
        const float4 g = *reinterpret_cast<const float4*>(gt + (size_t)b * 128 + n * 4);

        const float gx = g.x * S;
        const float gy = g.y * S;
        int col = (int)gx; col = min(max(col, 0), Wd - 1);
        int row = (int)gy; row = min(max(row, 0), Wd - 1);
        const float off_x = gx - (float)col;
        const float off_y = gy - (float)row;

        int col_n, row_n; bool vx, vy;
        if (off_x < 0.5f) { col_n = col - 1; vx = (col > 0); }
        else              { col_n = col + 1; vx = (col < Wd - 1); }
        if (off_y < 0.5f) { row_n = row - 1; vy = (row > 0); }
        else              { row_n = row + 1; vy = (row < Wd - 1); }

        int cs[3];
        cs[0] = row * Wd + col;
        cs[1] = vx ? (row * Wd + col_n) : -1;
        cs[2] = vy ? (row_n * Wd + col) : -1;

        // speculative channel gathers — issue BEFORE the LDS scatter round so the
        // cold-HBM latency overlaps it; dummy-index invalid candidates
        const float* base = pred + (size_t)b * 5 * HW;
        float pl0[3], pl1[3], pl2[3], pl3[3], pl4[3];
        #pragma unroll
        for (int k = 0; k < 3; k++) {
            const int cc = (cs[k] >= 0) ? cs[k] : cs[0];
            pl0[k] = base[cc];
            pl1[k] = base[HW + cc];
            pl2[k] = base[2 * HW + cc];
            pl3[k] = base[3 * HW + cc];
            pl4[k] = base[4 * HW + cc];
        }

        // init touched cells, scatter-max gi, read winners — single wave, LDS-only fences
        smap[cs[0]] = -1;
        if (cs[1] >= 0) smap[cs[1]] = -1;
        if (cs[2] >= 0) smap[cs[2]] = -1;
        __threadfence_block();
        atomicMax(&smap[cs[0]], n);
        if (cs[1] >= 0) atomicMax(&smap[cs[1]], n);
        if (cs[2] >= 0) atomicMax(&smap[cs[2]], n);
        __threadfence_block();

        // winner smap[c]==n  =>  winning gt row is THIS lane's g (in registers)
        const float t_cx = g.x, t_cy = g.y, t_w = g.z, t_h = g.w;
        const float b2x1 = t_cx - t_w * 0.5f, b2y1 = t_cy - t_h * 0.5f;
        const float b2x2 = t_cx + t_w * 0.5f, b2y2 = t_cy + t_h * 0.5f;
        const float w2 = b2x2 - b2x1, h2 = b2y2 - b2y1;
        const float atan2_ = atanf(w2 / (h2 + EPS));
        const float area_t = fmaxf(t_w * t_h, EPS);

        #pragma unroll
        for (int k = 0; k < 3; k++) {
            const int c = cs[k];
            if (c >= 0 && smap[c] == n) {
                np_v += 1.0f;
                const float l0 = pl0[k];
                const float ccol = (float)(c % Wd);
                const float crow = (float)(c / Wd);
                const float p_cx = (sigmoidf_(pl1[k]) * 2.0f - 0.5f + ccol) * sc;
                const float p_cy = (sigmoidf_(pl2[k]) * 2.0f - 0.5f + crow) * sc;
                const float p_w  = expf(fminf(fmaxf(pl3[k], -5.0f), 5.0f)) * sc;
                const float p_h  = expf(fminf(fmaxf(pl4[k], -5.0f), 5.0f)) * sc;

                const float b1x1 = p_cx - p_w * 0.5f, b1y1 = p_cy - p_h * 0.5f;
                const float b1x2 = p_cx + p_w * 0.5f, b1y2 = p_cy + p_h * 0.5f;
                const float w1 = b1x2 - b1x1, h1 = b1y2 - b1y1;

                const float iw = fmaxf(fminf(b1x2, b2x2) - fmaxf(b1x1, b2x1), 0.0f);
                const float ih = fmaxf(fminf(b1y2, b2y2) - fmaxf(b1y1, b2y1), 0.0f);
                const float inter = iw * ih;
                const float uni = w1 * h1 + w2 * h2 - inter + EPS;
                const float iou = inter / uni;

                const float cw = fmaxf(b1x2, b2x2) - fminf(b1x1, b2x1);
                const float ch = fmaxf(b1y2, b2y2) - fminf(b1y1, b2y1);
                const float c2 = cw * cw + ch * ch + EPS;
                const float dx = b2x1 + b2x2 - b1x1 - b1x2;
                const float dy = b2y1 + b2y2 - b1y1 - b1y2;
                const float rho2 = (dx * dx + dy * dy) * 0.25f;
                const float datan = atan2_ - atanf(w1 / (h1 + EPS));
                const float v = (4.0f / (float)(M_PI * M_PI)) * datan * datan;
                const float alpha = v / (v - iou + 1.0f + EPS);
                const float ciou = 1.0f - iou + rho2 / c2 + alpha * v;
                box_v += fmaxf(ciou, 0.0f);

                const float area_p = fmaxf(p_w * p_h, EPS);
                float iou2 = inter / (area_p + area_t - inter + EPS);
                iou2 = fminf(fmaxf(iou2, 0.0f), 1.0f);
                corr_v += l0 * iou2;          // BCE correction: -sum(l0*obj_t)
            }
        }
    }

    // 64-lane wave reduce (lanes 32-63 hold zeros)
    for (int off = 32; off > 0; off >>= 1) {
        box_v  += __shfl_down(box_v, off);
        corr_v += __shfl_down(corr_v, off);
        np_v   += __shfl_down(np_v, off);
    }
    if (lane == 0) {
        const float np = np_v;
        ws_pl[pbid] = make_float4(box_v / fmaxf(np, 1.0f), corr_v, np, (np > 0.0f) ? 1.0f : 0.0f);
    }
}

__global__ __launch_bounds__(256) void det_final(
    const float*  __restrict__ ws_c,
    const float4* __restrict__ ws_pl,
    int nPL,                              // 3B
    float* __restrict__ out)
{
    __shared__ float s_f[20];
    const int tid = threadIdx.x;
    float box = 0.0f, corr = 0.0f, bce = 0.0f, pos = 0.0f, items = 0.0f;
    for (int i = tid; i < nPL; i += 256) {
        const float4 v = ws_pl[i];
        box += v.x; corr += v.y; pos += v.z; items += v.w;
    }
    for (int i = tid; i < NB_BCE; i += 256) bce += ws_c[i];

    for (int off = 32; off > 0; off >>= 1) {
        box   += __shfl_down(box, off);
        corr  += __shfl_down(corr, off);
        bce   += __shfl_down(bce, off);
        pos   += __shfl_down(pos, off);
        items += __shfl_down(items, off);
    }
    const int wave = tid >> 6;
    if ((tid & 63) == 0) {
        s_f[wave * 5 + 0] = box;
        s_f[wave * 5 + 1] = corr;
        s_f[wave * 5 + 2] = bce;
        s_f[wave * 5 + 3] = pos;
        s_f[wave * 5 + 4] = items;
    }
    __syncthreads();
    if (tid == 0) {
        float box_t = 0.0f, corr_t = 0.0f, bce_t = 0.0f, pos_t = 0.0f, it_t = 0.0f;
        for (int w = 0; w < 4; w++) {
            box_t  += s_f[w * 5 + 0];
            corr_t += s_f[w * 5 + 1];
            bce_t  += s_f[w * 5 + 2];
            pos_t  += s_f[w * 5 + 3];
            it_t   += s_f[w * 5 + 4];
        }
        const float total_obj = (bce_t - corr_t) / fmaxf(pos_t, 1.0f);
        const float total_box = box_t / fmaxf(it_t, 1.0f);
        out[0] = total_obj + 5.0f * total_box;
    }
}

extern "C" void kernel_launch(void* const* d_in, const int* in_sizes, int n_in,
                              void* d_out, int out_size, void* d_ws, size_t ws_size,
                              hipStream_t stream)
{
    const float* pred0 = (const float*)d_in[0];
    const float* pred1 = (const float*)d_in[1];
    const float* pred2 = (const float*)d_in[2];
    const float* gt    = (const float*)d_in[3];
    float* out = (float*)d_out;

    const int B   = in_sizes[3] / (32 * 4);   // 512
    const int nPL = 3 * B;                    // 1536

    // ws layout: ws_c[NB_BCE] floats | ws_pl[nPL] float4 (offset 2048 B, 16-aligned)
    float*  ws_c  = (float*)d_ws;
    float4* ws_pl = (float4*)((char*)d_ws + NB_BCE * sizeof(float));

    det_main<<<dim3(nPL / 4 + NB_BCE), dim3(256), 0, stream>>>(
        pred0, pred1, pred2, gt, ws_c, ws_pl, B);
    det_final<<<dim3(1), dim3(256), 0, stream>>>(ws_c, ws_pl, nPL, out);
}

// Round 9
// 15.118 us; speedup vs baseline: 1.0616x; 1.0616x over previous
//
#include <hip/hip_runtime.h>
#include <math.h>

#define EPS 1e-7f
#define NB_BCE 512    // blocks doing the BCE base-sum role (grid total = 3B + 512 = 2048)

// BCE-with-logits base term (target-independent part): max(l,0) + log1p(exp(-|l|))
__device__ __forceinline__ float bce_base(float l) {
    return fmaxf(l, 0.0f) + __logf(1.0f + __expf(-fabsf(l)));
}

__device__ __forceinline__ float sigmoidf_(float x) { return 1.0f / (1.0f + expf(-x)); }

// Kernel 1. Grid = 3B + NB_BCE = 2048 blocks = exactly one scheduling round.
//  blocks [0, 3B)           : per-(image,level) positives work, SINGLE WAVE, no barriers
//                             -> ws_pl[bid] = {box/max(np,1), corr, np, np>0}
//  blocks [3B, 3B+NB_BCE)   : BCE base sum, ILP-batched: 4 independently-guarded
//                             float4 loads + guarded E2 scalar, all issued in ONE
//                             vmcnt epoch (vs the old grid-stride loop's ~4 serial
//                             cold-miss epochs) -> ws_c[...]
// No global atomics, no device fences; plain stores to distinct slots only
// (inter-dispatch flush provides visibility to kernel 2 — proven r2/r5/r6/r7/r8).
__global__ __launch_bounds__(256) void det_main(
    const float* __restrict__ pred0,   // (B,5,52,52)
    const float* __restrict__ pred1,   // (B,5,26,26)
    const float* __restrict__ pred2,   // (B,5,13,13)
    const float* __restrict__ gt,      // (B,32,4)
    float*       ws_c,                 // [NB_BCE]
    float4*      ws_pl,                // [3B]
    int B)
{
    __shared__ int   s_map[52 * 52];
    __shared__ float s_redf[4];

    const int tid = threadIdx.x;
    const int bid = blockIdx.x;
    const int nPL = 3 * B;

    if (bid >= nPL) {
        // ---------------- BCE base role (ILP-batched loads) ----------------
        const int cbid = bid - nPL;                        // 0 .. NB_BCE-1
        const unsigned E0 = (unsigned)B * 2704u;
        const unsigned E1 = (unsigned)B * 676u;
        const unsigned E2 = (unsigned)B * 169u;
        const unsigned NV4 = (E0 + E1) >> 2;               // 432640 float4 items
        const unsigned STRIDE = NB_BCE * 256u;             // 131072 threads
        const unsigned gthread = (unsigned)cbid * 256u + tid;

        float acc = 0.0f;

        // 4 independent guarded float4 loads: 4*131072 = 524288 >= NV4 (full coverage)
        #pragma unroll
        for (int it = 0; it < 4; it++) {
            const unsigned v = gthread + (unsigned)it * STRIDE;
            if (v < NV4) {
                const unsigned idx = v << 2;
                const float* p;
                if (idx < E0) {
                    const unsigned b = idx / 2704u;
                    const unsigned i = idx - b * 2704u;
                    p = pred0 + (size_t)b * 13520u + i;
                } else {
                    const unsigned j = idx - E0;
                    const unsigned b = j / 676u;
                    const unsigned i = j - b * 676u;
                    p = pred1 + (size_t)b * 3380u + i;
                }
                const float4 l = *reinterpret_cast<const float4*>(p);
                acc += bce_base(l.x) + bce_base(l.y) + bce_base(l.z) + bce_base(l.w);
            }
        }
        // E2 tail (86528 scalars < 131072 threads): one guarded scalar load
        if (gthread < E2) {
            const unsigned b = gthread / 169u;
            const unsigned i = gthread - b * 169u;
            acc += bce_base(pred2[(size_t)b * 845u + i]);
        }

        for (int off = 32; off > 0; off >>= 1) acc += __shfl_down(acc, off);
        if ((tid & 63) == 0) s_redf[tid >> 6] = acc;
        __syncthreads();
        if (tid == 0) ws_c[cbid] = s_redf[0] + s_redf[1] + s_redf[2] + s_redf[3];
        return;
    }

    // ---------------- positives role: one wave, no barriers ----------------
    if (tid >= 64) return;                 // waves 1-3 exit; no __syncthreads below

    const int pbid  = bid;                 // 0 .. 3B-1
    const int level = pbid % 3;
    const int b     = pbid / 3;

    const float* pred;
    int Wd;
    if (level == 0)      { pred = pred0; Wd = 52; }
    else if (level == 1) { pred = pred1; Wd = 26; }
    else                 { pred = pred2; Wd = 13; }
    const int   HW = Wd * Wd;
    const float S  = (float)Wd;
    const float sc = 1.0f / S;

    float box_v = 0.0f, corr_v = 0.0f, np_v = 0.0f;

    if (tid < 32) {
        const int n = tid;
        const float4 g = *reinterpret_cast<const float4*>(gt + (size_t)b * 128 + n * 4);

        const float gx = g.x * S;
        const float gy = g.y * S;
        int col = (int)gx; col = min(max(col, 0), Wd - 1);
        int row = (int)gy; row = min(max(row, 0), Wd - 1);
        const float off_x = gx - (float)col;
        const float off_y = gy - (float)row;

        int col_n, row_n; bool vx, vy;
        if (off_x < 0.5f) { col_n = col - 1; vx = (col > 0); }
        else              { col_n = col + 1; vx = (col < Wd - 1); }
        if (off_y < 0.5f) { row_n = row - 1; vy = (row > 0); }
        else              { row_n = row + 1; vy = (row < Wd - 1); }

        int cs[3];
        cs[0] = row * Wd + col;
        cs[1] = vx ? (row * Wd + col_n) : -1;
        cs[2] = vy ? (row_n * Wd + col) : -1;

        // init touched cells, scatter-max gi, read winners — single wave, LDS-only fences
        s_map[cs[0]] = -1;
        if (cs[1] >= 0) s_map[cs[1]] = -1;
        if (cs[2] >= 0) s_map[cs[2]] = -1;
        __threadfence_block();
        atomicMax(&s_map[cs[0]], n);
        if (cs[1] >= 0) atomicMax(&s_map[cs[1]], n);
        if (cs[2] >= 0) atomicMax(&s_map[cs[2]], n);
        __threadfence_block();

        const float* base = pred + (size_t)b * 5 * HW;

        // winner s_map[c]==n  =>  winning gt row is THIS lane's g (in registers)
        const float t_cx = g.x, t_cy = g.y, t_w = g.z, t_h = g.w;
        const float b2x1 = t_cx - t_w * 0.5f, b2y1 = t_cy - t_h * 0.5f;
        const float b2x2 = t_cx + t_w * 0.5f, b2y2 = t_cy + t_h * 0.5f;
        const float w2 = b2x2 - b2x1, h2 = b2y2 - b2y1;
        const float atan2_ = atanf(w2 / (h2 + EPS));
        const float area_t = fmaxf(t_w * t_h, EPS);

        #pragma unroll
        for (int k = 0; k < 3; k++) {
            const int c = cs[k];
            if (c >= 0 && s_map[c] == n) {
                np_v += 1.0f;
                const float l0 = base[c];
                const float l1 = base[HW + c];
                const float l2 = base[2 * HW + c];
                const float l3 = base[3 * HW + c];
                const float l4 = base[4 * HW + c];
                const float ccol = (float)(c % Wd);
                const float crow = (float)(c / Wd);
                const float p_cx = (sigmoidf_(l1) * 2.0f - 0.5f + ccol) * sc;
                const float p_cy = (sigmoidf_(l2) * 2.0f - 0.5f + crow) * sc;
                const float p_w  = expf(fminf(fmaxf(l3, -5.0f), 5.0f)) * sc;
                const float p_h  = expf(fminf(fmaxf(l4, -5.0f), 5.0f)) * sc;

                const float b1x1 = p_cx - p_w * 0.5f, b1y1 = p_cy - p_h * 0.5f;
                const float b1x2 = p_cx + p_w * 0.5f, b1y2 = p_cy + p_h * 0.5f;
                const float w1 = b1x2 - b1x1, h1 = b1y2 - b1y1;

                const float iw = fmaxf(fminf(b1x2, b2x2) - fmaxf(b1x1, b2x1), 0.0f);
                const float ih = fmaxf(fminf(b1y2, b2y2) - fmaxf(b1y1, b2y1), 0.0f);
                const float inter = iw * ih;
                const float uni = w1 * h1 + w2 * h2 - inter + EPS;
                const float iou = inter / uni;

                const float cw = fmaxf(b1x2, b2x2) - fminf(b1x1, b2x1);
                const float ch = fmaxf(b1y2, b2y2) - fminf(b1y1, b2y1);
                const float c2 = cw * cw + ch * ch + EPS;
                const float dx = b2x1 + b2x2 - b1x1 - b1x2;
                const float dy = b2y1 + b2y2 - b1y1 - b1y2;
                const float rho2 = (dx * dx + dy * dy) * 0.25f;
                const float datan = atan2_ - atanf(w1 / (h1 + EPS));
                const float v = (4.0f / (float)(M_PI * M_PI)) * datan * datan;
                const float alpha = v / (v - iou + 1.0f + EPS);
                const float ciou = 1.0f - iou + rho2 / c2 + alpha * v;
                box_v += fmaxf(ciou, 0.0f);

                const float area_p = fmaxf(p_w * p_h, EPS);
                float iou2 = inter / (area_p + area_t - inter + EPS);
                iou2 = fminf(fmaxf(iou2, 0.0f), 1.0f);
                corr_v += l0 * iou2;          // BCE correction: -sum(l0*obj_t)
            }
        }
    }

    // 64-lane wave reduce (lanes 32-63 hold zeros)
    for (int off = 32; off > 0; off >>= 1) {
        box_v  += __shfl_down(box_v, off);
        corr_v += __shfl_down(corr_v, off);
        np_v   += __shfl_down(np_v, off);
    }
    if (tid == 0) {
        const float np = np_v;
        ws_pl[pbid] = make_float4(box_v / fmaxf(np, 1.0f), corr_v, np, (np > 0.0f) ? 1.0f : 0.0f);
    }
}

__global__ __launch_bounds__(256) void det_final(
    const float*  __restrict__ ws_c,
    const float4* __restrict__ ws_pl,
    int nPL,                              // 3B
    float* __restrict__ out)
{
    __shared__ float s_f[20];
    const int tid = threadIdx.x;
    float box = 0.0f, corr = 0.0f, bce = 0.0f, pos = 0.0f, items = 0.0f;
    for (int i = tid; i < nPL; i += 256) {
        const float4 v = ws_pl[i];
        box += v.x; corr += v.y; pos += v.z; items += v.w;
    }
    for (int i = tid; i < NB_BCE; i += 256) bce += ws_c[i];

    for (int off = 32; off > 0; off >>= 1) {
        box   += __shfl_down(box, off);
        corr  += __shfl_down(corr, off);
        bce   += __shfl_down(bce, off);
        pos   += __shfl_down(pos, off);
        items += __shfl_down(items, off);
    }
    const int wave = tid >> 6;
    if ((tid & 63) == 0) {
        s_f[wave * 5 + 0] = box;
        s_f[wave * 5 + 1] = corr;
        s_f[wave * 5 + 2] = bce;
        s_f[wave * 5 + 3] = pos;
        s_f[wave * 5 + 4] = items;
    }
    __syncthreads();
    if (tid == 0) {
        float box_t = 0.0f, corr_t = 0.0f, bce_t = 0.0f, pos_t = 0.0f, it_t = 0.0f;
        for (int w = 0; w < 4; w++) {
            box_t  += s_f[w * 5 + 0];
            corr_t += s_f[w * 5 + 1];
            bce_t  += s_f[w * 5 + 2];
            pos_t  += s_f[w * 5 + 3];
            it_t   += s_f[w * 5 + 4];
        }
        const float total_obj = (bce_t - corr_t) / fmaxf(pos_t, 1.0f);
        const float total_box = box_t / fmaxf(it_t, 1.0f);
        out[0] = total_obj + 5.0f * total_box;
    }
}

extern "C" void kernel_launch(void* const* d_in, const int* in_sizes, int n_in,
                              void* d_out, int out_size, void* d_ws, size_t ws_size,
                              hipStream_t stream)
{
    const float* pred0 = (const float*)d_in[0];
    const float* pred1 = (const float*)d_in[1];
    const float* pred2 = (const float*)d_in[2];
    const float* gt    = (const float*)d_in[3];
    float* out = (float*)d_out;

    const int B   = in_sizes[3] / (32 * 4);   // 512
    const int nPL = 3 * B;                    // 1536

    // ws layout: ws_c[NB_BCE] floats | ws_pl[nPL] float4 (offset 2048 B, 16-aligned)
    float*  ws_c  = (float*)d_ws;
    float4* ws_pl = (float4*)((char*)d_ws + NB_BCE * sizeof(float));

    det_main<<<dim3(nPL + NB_BCE), dim3(256), 0, stream>>>(
        pred0, pred1, pred2, gt, ws_c, ws_pl, B);
    det_final<<<dim3(1), dim3(256), 0, stream>>>(ws_c, ws_pl, nPL, out);
}